// Round 19
// baseline (98.903 us; speedup 1.0000x reference)
//
#include <hip/hip_runtime.h>

#define F_BINS  257
#define T_STEPS 65536
#define N_ACT   256
#define TM      128           // t-columns per k_gemm block (4 waves x 32t)
#define NBLK_G  512           // T_STEPS / TM
#define NTHR    256           // 4 waves
#define XO_PB   8224          // float4 per block: 4210688/512 exact (32/thr + 32 rem)

typedef float f32x4 __attribute__((ext_vector_type(4)));
typedef short s16x8 __attribute__((ext_vector_type(8)));
typedef unsigned u32x4 __attribute__((ext_vector_type(4)));

// ws layout (all fully written every call - no memset needed):
//   [1024]   double partial[NBLK_G=512]  (per-block xo^2 sums)
//   [20480]  double corrp[257]           (per-f correction sums)
//   [24576]  unsigned maskp[NBLK_G*8]
//   [65536]  uchar Gfrag[147456]         (B frags: [kk][ng][lane][16B])
#define WS_PART  1024
#define WS_CORR  20480
#define WS_MASK  24576
#define WS_GFRAG 65536

__device__ __forceinline__ unsigned short f2bf_rne(float x) {
  unsigned u = __builtin_bit_cast(unsigned, x);
  return (unsigned short)((u + 0x7FFFu + ((u >> 16) & 1u)) >> 16);
}
// bf16(hi)<<16 | bf16(lo) by truncation: one v_perm_b32
__device__ __forceinline__ unsigned pack_bf(float hi, float lo) {
  return __builtin_amdgcn_perm(__builtin_bit_cast(unsigned, hi),
                               __builtin_bit_cast(unsigned, lo), 0x07060302u);
}

// ---------------------------------------------------------------------------
// B fragments in MFMA order:
// Gfrag[((kk*16+ng)*64+lane)*16] = 8 bf16 of G[f=32kk+8(lane>>4)+j][a=16ng+(lane&15)]
// ---------------------------------------------------------------------------
__global__ __launch_bounds__(256) void k_prep(const float* __restrict__ G,
                                              unsigned char* __restrict__ gfrag) {
  const int u = blockIdx.x * 256 + threadIdx.x;   // 0..9215
  const int lane = u & 63, ng = (u >> 6) & 15, kk = u >> 10;
  const int r16 = lane & 15, g = lane >> 4;
  const int a = ng * 16 + r16;
  unsigned short h[8];
#pragma unroll
  for (int j = 0; j < 8; ++j) {
    const int f = kk * 32 + 8 * g + j;
    h[j] = (f < F_BINS) ? f2bf_rne(G[f * N_ACT + a]) : (unsigned short)0;
  }
  u32x4 w;
#pragma unroll
  for (int i = 0; i < 4; ++i)
    w[i] = (unsigned)h[2 * i] | ((unsigned)h[2 * i + 1] << 16);
  *(u32x4*)(gfrag + (size_t)u * 16) = w;
}

// ---------------------------------------------------------------------------
// GEMM+argmax+xo^2 at 4 blocks/CU: quarter-B staging (36KB LDS), 4 MFMA
// passes over action-quarters with 3 restages; deeper cross-block phase
// drift hides each block's serial phases. A fully preloaded to af[9][2]
// (depth-2 batch window to fit the 128-VGPR cap); xo epilogue from R18.
// ---------------------------------------------------------------------------
__global__ __launch_bounds__(NTHR, 4) void k_gemm(
    const float* __restrict__ xs, const float4* __restrict__ xo4,
    const unsigned char* __restrict__ gfrag,
    unsigned* __restrict__ maskp, double* __restrict__ partial) {
  const int tid = threadIdx.x, lane = tid & 63, wv = tid >> 6;
  const int g = lane >> 4, r16 = lane & 15;
  const int t0 = blockIdx.x * TM;
  const int tcol = t0 + 32 * wv + 2 * r16;   // float2 load column

  __shared__ __align__(16) unsigned char Bq[36864];  // one action-quarter of B
  __shared__ unsigned lmask[8];
  __shared__ double sdw[4];
  if (tid < 8) lmask[tid] = 0u;

  // stage action-quarter qv (64 actions): 36 x 1KB; wave wv does 9wv..9wv+8
#define STAGE_BQ(qv)                                                          \
  {                                                                           \
    _Pragma("unroll") for (int idx = 0; idx < 9; ++idx) {                     \
      const int j = 9 * wv + idx;          /* 0..35: dst chunk */             \
      const int kkc = j >> 2, ic = j & 3;                                     \
      const unsigned char* src = gfrag +                                      \
          (size_t)(kkc * 16 + 4 * (qv) + ic) * 1024 + (size_t)lane * 16;      \
      unsigned char* dst = &Bq[j * 1024];                                     \
      __builtin_amdgcn_global_load_lds(                                       \
          (const __attribute__((address_space(1))) unsigned*)src,             \
          (__attribute__((address_space(3))) unsigned*)dst, 16, 0, 0);        \
    }                                                                         \
  }
  // A batch: 8 float2 loads (f-rows 32kkv+8g..+8g+7 at fixed 2 t's)
#define LOADB(slot, kkv)                                                      \
  {                                                                           \
    _Pragma("unroll") for (int j = 0; j < 8; ++j) {                           \
      int f = 32 * (kkv) + 8 * g + j;                                         \
      if ((kkv) == 8) f = f > 256 ? 256 : f; /* Gfrag zero rows cover pad */  \
      va[slot][j] = *(const float2*)(xs + (size_t)f * T_STEPS + tcol);        \
    }                                                                         \
  }

  float2 va[2][8];
  LOADB(0, 0) LOADB(1, 1)
  __builtin_amdgcn_sched_barrier(0);
  STAGE_BQ(0)                      // after A batches 0-1, before 2-8
  __builtin_amdgcn_sched_barrier(0);

  // pack all A fragments while later batches stream in (depth-2 window)
  s16x8 af[9][2];   // [kk][tau], 72 VGPR
#pragma unroll
  for (int kk = 0; kk < 9; ++kk) {
    const int b = kk & 1;
    af[kk][0] = __builtin_bit_cast(s16x8, (u32x4){
        pack_bf(va[b][1].x, va[b][0].x), pack_bf(va[b][3].x, va[b][2].x),
        pack_bf(va[b][5].x, va[b][4].x), pack_bf(va[b][7].x, va[b][6].x)});
    af[kk][1] = __builtin_bit_cast(s16x8, (u32x4){
        pack_bf(va[b][1].y, va[b][0].y), pack_bf(va[b][3].y, va[b][2].y),
        pack_bf(va[b][5].y, va[b][4].y), pack_bf(va[b][7].y, va[b][6].y)});
    if (kk + 2 <= 8) LOADB(b, kk + 2)
  }
#undef LOADB

  __syncthreads();   // drains vmcnt (quarter 0 staged) + all waves arrived

  // ---- four action-quarter passes; argmax folds across q in registers ----
  float bv[2][4]; int bc[2][4];
#pragma unroll
  for (int q4 = 0; q4 < 4; ++q4) {
    if (q4 >= 1) {
      __syncthreads();             // everyone done reading quarter q4-1
      STAGE_BQ(q4)
      __syncthreads();             // quarter q4 staged (vmcnt drained)
    }
    f32x4 acc[2][4];   // [tau][n]
#pragma unroll
    for (int tau = 0; tau < 2; ++tau)
#pragma unroll
      for (int n = 0; n < 4; ++n) acc[tau][n] = (f32x4){0.f, 0.f, 0.f, 0.f};
#pragma unroll
    for (int kk = 0; kk < 9; ++kk) {
      const unsigned char* bp = &Bq[(kk * 4 * 64 + lane) * 16];
#pragma unroll
      for (int n = 0; n < 4; ++n) {
        const s16x8 bfr = *(const s16x8*)(bp + n * 1024);
        acc[0][n] = __builtin_amdgcn_mfma_f32_16x16x32_bf16(
            af[kk][0], bfr, acc[0][n], 0, 0, 0);
        acc[1][n] = __builtin_amdgcn_mfma_f32_16x16x32_bf16(
            af[kk][1], bfr, acc[1][n], 0, 0, 0);
      }
    }
    // fold into running argmax: a = 64q4 + 16n + r16 (ascending => first-min)
#pragma unroll
    for (int n = 0; n < 4; ++n) {
      const int c = 64 * q4 + 16 * n + r16;
#pragma unroll
      for (int tau = 0; tau < 2; ++tau)
#pragma unroll
        for (int q = 0; q < 4; ++q) {
          const float v = acc[tau][n][q];
          if (q4 == 0 && n == 0) { bv[tau][q] = v; bc[tau][q] = c; }
          else if (v > bv[tau][q]) { bv[tau][q] = v; bc[tau][q] = c; }
        }
    }
  }
#undef STAGE_BQ

  // ---- issue xo round 0 + remainder early: argmax shuffles hide the ramp --
  const float4* xop = xo4 + (size_t)blockIdx.x * XO_PB + tid;
  float4 xv[2][8];
#pragma unroll
  for (int j = 0; j < 8; ++j) xv[0][j] = xop[j * 256];
  float4 wrem = (float4){0.f, 0.f, 0.f, 0.f};
  if (tid < 32) wrem = xo4[(size_t)blockIdx.x * XO_PB + 8192 + tid];

  // cross-lane (r16) argmax; each lane's t = t0+32wv+2*(4g+q)+tau
#pragma unroll
  for (int m = 1; m <= 8; m <<= 1) {
#pragma unroll
    for (int tau = 0; tau < 2; ++tau)
#pragma unroll
      for (int q = 0; q < 4; ++q) {
        const float ov = __shfl_xor(bv[tau][q], m);
        const int   oc = __shfl_xor(bc[tau][q], m);
        if (ov > bv[tau][q] || (ov == bv[tau][q] && oc < bc[tau][q])) {
          bv[tau][q] = ov; bc[tau][q] = oc;
        }
      }
  }
  if (r16 == 0) {
#pragma unroll
    for (int tau = 0; tau < 2; ++tau)
#pragma unroll
      for (int q = 0; q < 4; ++q)
        atomicOr(&lmask[bc[tau][q] >> 5], 1u << (bc[tau][q] & 31));
  }
  __syncthreads();
  if (tid < 8) maskp[blockIdx.x * 8 + tid] = lmask[tid];

  // ---- xo main: 4 rounds x 8 float4, double-buffered ----
  double ds = 0.0;
#pragma unroll
  for (int r = 0; r < 4; ++r) {
    if (r + 1 < 4) {
#pragma unroll
      for (int j = 0; j < 8; ++j)
        xv[(r + 1) & 1][j] = xop[(size_t)(r + 1) * 2048 + j * 256];
    }
    const float4* xc = xv[r & 1];
    float fs = 0.f;
#pragma unroll
    for (int j = 0; j < 8; ++j) {
      fs = fmaf(xc[j].x, xc[j].x, fs); fs = fmaf(xc[j].y, xc[j].y, fs);
      fs = fmaf(xc[j].z, xc[j].z, fs); fs = fmaf(xc[j].w, xc[j].w, fs);
    }
    ds += (double)fs;
  }
  {
    float fs = 0.f;
    fs = fmaf(wrem.x, wrem.x, fs); fs = fmaf(wrem.y, wrem.y, fs);
    fs = fmaf(wrem.z, wrem.z, fs); fs = fmaf(wrem.w, wrem.w, fs);
    ds += (double)fs;
  }
#pragma unroll
  for (int off = 32; off; off >>= 1) ds += __shfl_down(ds, off);
  if (lane == 0) sdw[wv] = ds;
  __syncthreads();
  if (tid == 0) partial[blockIdx.x] = sdw[0] + sdw[1] + sdw[2] + sdw[3];
}

// ---------------------------------------------------------------------------
// OR-reduce per-block masks (NBLK_G=512), then correction for columns t = a:
//   corrp[f] = sum_a sel[a] * ((G*xs)^2 - 2*(G*xs)*xo)
// ---------------------------------------------------------------------------
__global__ __launch_bounds__(256) void k_corr(
    const float* __restrict__ xs, const float* __restrict__ xo,
    const float* __restrict__ G, const unsigned* __restrict__ maskp,
    double* __restrict__ corrp) {
  __shared__ unsigned m8[8];
  const int tid = threadIdx.x;
  if (tid < 8) m8[tid] = 0u;
  __syncthreads();
  unsigned m = 0;
  for (int b = tid >> 3; b < NBLK_G; b += 32) m |= maskp[b * 8 + (tid & 7)];
  atomicOr(&m8[tid & 7], m);
  __syncthreads();
  const int f = blockIdx.x, a = tid;
  const bool sel = (m8[a >> 5] >> (a & 31)) & 1u;
  const float gv  = G[f * N_ACT + a];
  const float xsv = xs[(size_t)f * T_STEPS + a];
  const float xov = xo[(size_t)f * T_STEPS + a];
  const float gx  = gv * xsv;
  double acc = sel ? (double)(gx * (gx - 2.f * xov)) : 0.0;
#pragma unroll
  for (int off = 32; off; off >>= 1) acc += __shfl_down(acc, off);
  __shared__ double sdc[4];
  if ((tid & 63) == 0) sdc[tid >> 6] = acc;
  __syncthreads();
  if (tid == 0) corrp[f] = sdc[0] + sdc[1] + sdc[2] + sdc[3];
}

// ---------------------------------------------------------------------------
// Final reduction: partial[512] + corrp[257] -> loss
// ---------------------------------------------------------------------------
__global__ __launch_bounds__(256) void k_final(const double* __restrict__ partial,
                                               const double* __restrict__ corrp,
                                               float* __restrict__ out) {
  const int tid = threadIdx.x;
  double s = partial[tid] + partial[tid + 256] + corrp[tid];
  if (tid == 0) s += corrp[256];
#pragma unroll
  for (int off = 32; off; off >>= 1) s += __shfl_down(s, off);
  __shared__ double sd[4];
  if ((tid & 63) == 0) sd[tid >> 6] = s;
  __syncthreads();
  if (tid == 0)
    out[0] = (float)((sd[0] + sd[1] + sd[2] + sd[3]) /
                     ((double)F_BINS * (double)T_STEPS));
}

extern "C" void kernel_launch(void* const* d_in, const int* in_sizes, int n_in,
                              void* d_out, int out_size, void* d_ws, size_t ws_size,
                              hipStream_t stream) {
  const float* x_out    = (const float*)d_in[0];
  const float* x_source = (const float*)d_in[1];
  // d_in[2] (x_clean) is dead: argmin_a(clean_sum - proj) == argmax_a proj
  const float* G        = (const float*)d_in[3];

  char* ws = (char*)d_ws;
  double*        partial = (double*)(ws + WS_PART);
  double*        corrp   = (double*)(ws + WS_CORR);
  unsigned*      maskp   = (unsigned*)(ws + WS_MASK);
  unsigned char* gfrag   = (unsigned char*)(ws + WS_GFRAG);

  // no memset: partial, corrp, maskp, gfrag fully written every call
  k_prep <<<36, 256, 0, stream>>>(G, gfrag);
  k_gemm <<<NBLK_G, NTHR, 0, stream>>>(x_source, (const float4*)x_out,
                                       gfrag, maskp, partial);
  k_corr <<<F_BINS, 256, 0, stream>>>(x_source, x_out, G, maskp, corrp);
  k_final<<<1, 256, 0, stream>>>(partial, corrp, (float*)d_out);
}

// Round 20
// 49.855 us; speedup vs baseline: 1.9838x; 1.9838x over previous
//
#include <hip/hip_runtime.h>

#define F_BINS  257
#define T_STEPS 65536
#define N_ACT   256
#define TM      128           // t-columns per k_gemm block (4 waves x 32t)
#define NBLK_G  512           // T_STEPS / TM  -> 2 blocks/CU
#define NTHR    256           // 4 waves
#define XO_PB   8224          // float4 per block: 4210688/512 exact (32/thr + 32 rem)

typedef float f32x4 __attribute__((ext_vector_type(4)));
typedef short s16x8 __attribute__((ext_vector_type(8)));
typedef unsigned u32x4 __attribute__((ext_vector_type(4)));

// ws layout:
//   [1024]   double partial[NBLK_G=512]  (per-block xo^2 sums; fully written)
//   [20480]  double corrp[257]           (per-f correction sums; fully written)
//   [24000]  unsigned done_counter       (memset to 0 each call)
//   [24576]  unsigned maskp[NBLK_G*8]    (fully written)
//   [65536]  uchar Gfrag[147456]         (B frags: [kk][ng][lane][16B]; fully written)
#define WS_PART  1024
#define WS_CORR  20480
#define WS_CNT   24000
#define WS_MASK  24576
#define WS_GFRAG 65536

__device__ __forceinline__ unsigned short f2bf_rne(float x) {
  unsigned u = __builtin_bit_cast(unsigned, x);
  return (unsigned short)((u + 0x7FFFu + ((u >> 16) & 1u)) >> 16);
}
// bf16(hi)<<16 | bf16(lo) by truncation: one v_perm_b32
__device__ __forceinline__ unsigned pack_bf(float hi, float lo) {
  return __builtin_amdgcn_perm(__builtin_bit_cast(unsigned, hi),
                               __builtin_bit_cast(unsigned, lo), 0x07060302u);
}

// ---------------------------------------------------------------------------
// B fragments in MFMA order:
// Gfrag[((kk*16+ng)*64+lane)*16] = 8 bf16 of G[f=32kk+8(lane>>4)+j][a=16ng+(lane&15)]
// ---------------------------------------------------------------------------
__global__ __launch_bounds__(256) void k_prep(const float* __restrict__ G,
                                              unsigned char* __restrict__ gfrag) {
  const int u = blockIdx.x * 256 + threadIdx.x;   // 0..9215
  const int lane = u & 63, ng = (u >> 6) & 15, kk = u >> 10;
  const int r16 = lane & 15, g = lane >> 4;
  const int a = ng * 16 + r16;
  unsigned short h[8];
#pragma unroll
  for (int j = 0; j < 8; ++j) {
    const int f = kk * 32 + 8 * g + j;
    h[j] = (f < F_BINS) ? f2bf_rne(G[f * N_ACT + a]) : (unsigned short)0;
  }
  u32x4 w;
#pragma unroll
  for (int i = 0; i < 4; ++i)
    w[i] = (unsigned)h[2 * i] | ((unsigned)h[2 * i + 1] << 16);
  *(u32x4*)(gfrag + (size_t)u * 16) = w;
}

// ---------------------------------------------------------------------------
// GEMM+argmax+xo^2, 2 blocks/CU — byte-identical to R18 (passed, 41.7us).
// ---------------------------------------------------------------------------
__global__ __launch_bounds__(NTHR, 2) void k_gemm(
    const float* __restrict__ xs, const float4* __restrict__ xo4,
    const unsigned char* __restrict__ gfrag,
    unsigned* __restrict__ maskp, double* __restrict__ partial) {
  const int tid = threadIdx.x, lane = tid & 63, wv = tid >> 6;
  const int g = lane >> 4, r16 = lane & 15;
  const int t0 = blockIdx.x * TM;
  const int tcol = t0 + 32 * wv + 2 * r16;   // float2 load column

  __shared__ __align__(16) unsigned char Bh[73728];  // one action-half of B
  __shared__ unsigned lmask[8];
  __shared__ double sdw[4];
  if (tid < 8) lmask[tid] = 0u;

  // stage action-half hv: 72 chunks of 1KB; wave wv does idx 18wv..18wv+17
#define STAGE_BH(hv)                                                          \
  {                                                                           \
    _Pragma("unroll") for (int idx = 0; idx < 18; ++idx) {                    \
      const int j = 18 * wv + idx;         /* 0..71: dst chunk */             \
      const int kkc = j >> 3, ic = j & 7;                                     \
      const unsigned char* src = gfrag +                                      \
          (size_t)(kkc * 16 + 8 * (hv) + ic) * 1024 + (size_t)lane * 16;      \
      unsigned char* dst = &Bh[j * 1024];                                     \
      __builtin_amdgcn_global_load_lds(                                       \
          (const __attribute__((address_space(1))) unsigned*)src,             \
          (__attribute__((address_space(3))) unsigned*)dst, 16, 0, 0);        \
    }                                                                         \
  }
  // A batch: 8 float2 loads (f-rows 32kkv+8g..+8g+7 at fixed 2 t's)
#define LOADB(slot, kkv)                                                      \
  {                                                                           \
    _Pragma("unroll") for (int j = 0; j < 8; ++j) {                           \
      int f = 32 * (kkv) + 8 * g + j;                                         \
      if ((kkv) == 8) f = f > 256 ? 256 : f; /* Gfrag zero rows cover pad */  \
      va[slot][j] = *(const float2*)(xs + (size_t)f * T_STEPS + tcol);        \
    }                                                                         \
  }

  float2 va[4][8];
  LOADB(0, 0) LOADB(1, 1) LOADB(2, 2) LOADB(3, 3)
  __builtin_amdgcn_sched_barrier(0);
  STAGE_BH(0)                      // after A batches 0-3, before 4-8
  __builtin_amdgcn_sched_barrier(0);

  // pack all A fragments while later batches stream in
  s16x8 af[9][2];   // [kk][tau], 72 VGPR
#pragma unroll
  for (int kk = 0; kk < 9; ++kk) {
    const int b = kk & 3;
    af[kk][0] = __builtin_bit_cast(s16x8, (u32x4){
        pack_bf(va[b][1].x, va[b][0].x), pack_bf(va[b][3].x, va[b][2].x),
        pack_bf(va[b][5].x, va[b][4].x), pack_bf(va[b][7].x, va[b][6].x)});
    af[kk][1] = __builtin_bit_cast(s16x8, (u32x4){
        pack_bf(va[b][1].y, va[b][0].y), pack_bf(va[b][3].y, va[b][2].y),
        pack_bf(va[b][5].y, va[b][4].y), pack_bf(va[b][7].y, va[b][6].y)});
    if (kk + 4 <= 8) LOADB(b, kk + 4)
  }
#undef LOADB

  __syncthreads();   // drains vmcnt (B half 0 staged) + all waves arrived

  // ---- two action-half passes; argmax folds across h in registers ----
  float bv[2][4]; int bc[2][4];
#pragma unroll
  for (int h = 0; h < 2; ++h) {
    if (h == 1) {
      __syncthreads();             // everyone done reading half 0
      STAGE_BH(1)
      __syncthreads();             // half 1 staged (vmcnt drained here)
    }
    f32x4 acc[2][8];   // [tau][n]
#pragma unroll
    for (int tau = 0; tau < 2; ++tau)
#pragma unroll
      for (int n = 0; n < 8; ++n) acc[tau][n] = (f32x4){0.f, 0.f, 0.f, 0.f};
#pragma unroll
    for (int kk = 0; kk < 9; ++kk) {
      const unsigned char* bp = &Bh[(kk * 8 * 64 + lane) * 16];
#pragma unroll
      for (int n = 0; n < 8; ++n) {
        const s16x8 bfr = *(const s16x8*)(bp + n * 1024);
        acc[0][n] = __builtin_amdgcn_mfma_f32_16x16x32_bf16(
            af[kk][0], bfr, acc[0][n], 0, 0, 0);
        acc[1][n] = __builtin_amdgcn_mfma_f32_16x16x32_bf16(
            af[kk][1], bfr, acc[1][n], 0, 0, 0);
      }
    }
    // fold into running argmax: a = 128h + 16n + r16 (ascending => first-min)
#pragma unroll
    for (int n = 0; n < 8; ++n) {
      const int c = 128 * h + 16 * n + r16;
#pragma unroll
      for (int tau = 0; tau < 2; ++tau)
#pragma unroll
        for (int q = 0; q < 4; ++q) {
          const float v = acc[tau][n][q];
          if (h == 0 && n == 0) { bv[tau][q] = v; bc[tau][q] = c; }
          else if (v > bv[tau][q]) { bv[tau][q] = v; bc[tau][q] = c; }
        }
    }
  }
#undef STAGE_BH

  // ---- issue xo round 0 + remainder early: argmax shuffles hide the ramp --
  const float4* xop = xo4 + (size_t)blockIdx.x * XO_PB + tid;
  float4 xv[2][8];
#pragma unroll
  for (int j = 0; j < 8; ++j) xv[0][j] = xop[j * 256];
  float4 wrem = (float4){0.f, 0.f, 0.f, 0.f};
  if (tid < 32) wrem = xo4[(size_t)blockIdx.x * XO_PB + 8192 + tid];

  // cross-lane (r16) argmax; each lane's t = t0+32wv+2*(4g+q)+tau
#pragma unroll
  for (int m = 1; m <= 8; m <<= 1) {
#pragma unroll
    for (int tau = 0; tau < 2; ++tau)
#pragma unroll
      for (int q = 0; q < 4; ++q) {
        const float ov = __shfl_xor(bv[tau][q], m);
        const int   oc = __shfl_xor(bc[tau][q], m);
        if (ov > bv[tau][q] || (ov == bv[tau][q] && oc < bc[tau][q])) {
          bv[tau][q] = ov; bc[tau][q] = oc;
        }
      }
  }
  if (r16 == 0) {
#pragma unroll
    for (int tau = 0; tau < 2; ++tau)
#pragma unroll
      for (int q = 0; q < 4; ++q)
        atomicOr(&lmask[bc[tau][q] >> 5], 1u << (bc[tau][q] & 31));
  }
  __syncthreads();
  if (tid < 8) maskp[blockIdx.x * 8 + tid] = lmask[tid];

  // ---- xo main: 4 rounds x 8 float4, double-buffered ----
  double ds = 0.0;
#pragma unroll
  for (int r = 0; r < 4; ++r) {
    if (r + 1 < 4) {
#pragma unroll
      for (int j = 0; j < 8; ++j)
        xv[(r + 1) & 1][j] = xop[(size_t)(r + 1) * 2048 + j * 256];
    }
    const float4* xc = xv[r & 1];
    float fs = 0.f;
#pragma unroll
    for (int j = 0; j < 8; ++j) {
      fs = fmaf(xc[j].x, xc[j].x, fs); fs = fmaf(xc[j].y, xc[j].y, fs);
      fs = fmaf(xc[j].z, xc[j].z, fs); fs = fmaf(xc[j].w, xc[j].w, fs);
    }
    ds += (double)fs;
  }
  {
    float fs = 0.f;
    fs = fmaf(wrem.x, wrem.x, fs); fs = fmaf(wrem.y, wrem.y, fs);
    fs = fmaf(wrem.z, wrem.z, fs); fs = fmaf(wrem.w, wrem.w, fs);
    ds += (double)fs;
  }
#pragma unroll
  for (int off = 32; off; off >>= 1) ds += __shfl_down(ds, off);
  if (lane == 0) sdw[wv] = ds;
  __syncthreads();
  if (tid == 0) partial[blockIdx.x] = sdw[0] + sdw[1] + sdw[2] + sdw[3];
}

// ---------------------------------------------------------------------------
// k_corr + fused final: OR-reduce per-block masks, compute corrp[f]; the
// LAST finishing block (device-scope ticket) reduces partial[512]+corrp[257]
// and writes the loss. Output is deterministic: the reducer always sums the
// same fixed arrays in the same tid order, whichever block it happens to be.
// ---------------------------------------------------------------------------
__global__ __launch_bounds__(256) void k_corr(
    const float* __restrict__ xs, const float* __restrict__ xo,
    const float* __restrict__ G, const unsigned* __restrict__ maskp,
    double* __restrict__ corrp, const double* __restrict__ partial,
    unsigned* __restrict__ done_counter, float* __restrict__ out) {
  __shared__ unsigned m8[8];
  __shared__ unsigned is_last;
  const int tid = threadIdx.x;
  if (tid < 8) m8[tid] = 0u;
  __syncthreads();
  unsigned m = 0;
  for (int b = tid >> 3; b < NBLK_G; b += 32) m |= maskp[b * 8 + (tid & 7)];
  atomicOr(&m8[tid & 7], m);
  __syncthreads();
  const int f = blockIdx.x, a = tid;
  const bool sel = (m8[a >> 5] >> (a & 31)) & 1u;
  const float gv  = G[f * N_ACT + a];
  const float xsv = xs[(size_t)f * T_STEPS + a];
  const float xov = xo[(size_t)f * T_STEPS + a];
  const float gx  = gv * xsv;
  double acc = sel ? (double)(gx * (gx - 2.f * xov)) : 0.0;
#pragma unroll
  for (int off = 32; off; off >>= 1) acc += __shfl_down(acc, off);
  __shared__ double sdc[4];
  if ((tid & 63) == 0) sdc[tid >> 6] = acc;
  __syncthreads();
  if (tid == 0) {
    corrp[f] = sdc[0] + sdc[1] + sdc[2] + sdc[3];
    __threadfence();                               // publish corrp[f]
    const unsigned ticket = atomicAdd(done_counter, 1u);
    is_last = (ticket == F_BINS - 1) ? 1u : 0u;
  }
  __syncthreads();
  if (!is_last) return;

  // last block: all corrp[] published; fence-acquire then reduce everything
  __threadfence();
  double s = partial[tid] + partial[tid + 256] + corrp[tid];
  if (tid == 0) s += corrp[256];
#pragma unroll
  for (int off = 32; off; off >>= 1) s += __shfl_down(s, off);
  __shared__ double sfin[4];
  if ((tid & 63) == 0) sfin[tid >> 6] = s;
  __syncthreads();
  if (tid == 0)
    out[0] = (float)((sfin[0] + sfin[1] + sfin[2] + sfin[3]) /
                     ((double)F_BINS * (double)T_STEPS));
}

extern "C" void kernel_launch(void* const* d_in, const int* in_sizes, int n_in,
                              void* d_out, int out_size, void* d_ws, size_t ws_size,
                              hipStream_t stream) {
  const float* x_out    = (const float*)d_in[0];
  const float* x_source = (const float*)d_in[1];
  // d_in[2] (x_clean) is dead: argmin_a(clean_sum - proj) == argmax_a proj
  const float* G        = (const float*)d_in[3];

  char* ws = (char*)d_ws;
  double*        partial = (double*)(ws + WS_PART);
  double*        corrp   = (double*)(ws + WS_CORR);
  unsigned*      counter = (unsigned*)(ws + WS_CNT);
  unsigned*      maskp   = (unsigned*)(ws + WS_MASK);
  unsigned char* gfrag   = (unsigned char*)(ws + WS_GFRAG);

  hipMemsetAsync(counter, 0, 4, stream);   // ticket reset; rest fully written
  k_prep <<<36, 256, 0, stream>>>(G, gfrag);
  k_gemm <<<NBLK_G, NTHR, 0, stream>>>(x_source, (const float4*)x_out,
                                       gfrag, maskp, partial);
  k_corr <<<F_BINS, 256, 0, stream>>>(x_source, x_out, G, maskp,
                                      corrp, partial, counter, (float*)d_out);
}

// Round 21
// 42.332 us; speedup vs baseline: 2.3364x; 1.1777x over previous
//
#include <hip/hip_runtime.h>

#define F_BINS  257
#define T_STEPS 65536
#define N_ACT   256
#define TM      128           // t-columns per k_gemm block (4 waves x 32t)
#define NBLK_G  512           // T_STEPS / TM  -> 2 blocks/CU
#define NTHR    256           // 4 waves
#define XO_PB   8224          // float4 per block: 4210688/512 exact (32/thr + 32 rem)

typedef float f32x4 __attribute__((ext_vector_type(4)));
typedef short s16x8 __attribute__((ext_vector_type(8)));
typedef unsigned u32x4 __attribute__((ext_vector_type(4)));

// ws layout (all fully written every call - no memset needed):
//   [1024]   double partial[NBLK_G=512]  (per-block xo^2 sums)
//   [20480]  double corrp[257]           (per-f correction sums)
//   [24576]  unsigned maskp[NBLK_G*8]
//   [65536]  uchar Gfrag[147456]         (B frags: [kk][ng][lane][16B])
#define WS_PART  1024
#define WS_CORR  20480
#define WS_MASK  24576
#define WS_GFRAG 65536

__device__ __forceinline__ unsigned short f2bf_rne(float x) {
  unsigned u = __builtin_bit_cast(unsigned, x);
  return (unsigned short)((u + 0x7FFFu + ((u >> 16) & 1u)) >> 16);
}
// bf16(hi)<<16 | bf16(lo) by truncation: one v_perm_b32
__device__ __forceinline__ unsigned pack_bf(float hi, float lo) {
  return __builtin_amdgcn_perm(__builtin_bit_cast(unsigned, hi),
                               __builtin_bit_cast(unsigned, lo), 0x07060302u);
}

// ---------------------------------------------------------------------------
// B fragments in MFMA order:
// Gfrag[((kk*16+ng)*64+lane)*16] = 8 bf16 of G[f=32kk+8(lane>>4)+j][a=16ng+(lane&15)]
// ---------------------------------------------------------------------------
__global__ __launch_bounds__(256) void k_prep(const float* __restrict__ G,
                                              unsigned char* __restrict__ gfrag) {
  const int u = blockIdx.x * 256 + threadIdx.x;   // 0..9215
  const int lane = u & 63, ng = (u >> 6) & 15, kk = u >> 10;
  const int r16 = lane & 15, g = lane >> 4;
  const int a = ng * 16 + r16;
  unsigned short h[8];
#pragma unroll
  for (int j = 0; j < 8; ++j) {
    const int f = kk * 32 + 8 * g + j;
    h[j] = (f < F_BINS) ? f2bf_rne(G[f * N_ACT + a]) : (unsigned short)0;
  }
  u32x4 w;
#pragma unroll
  for (int i = 0; i < 4; ++i)
    w[i] = (unsigned)h[2 * i] | ((unsigned)h[2 * i + 1] << 16);
  *(u32x4*)(gfrag + (size_t)u * 16) = w;
}

// ---------------------------------------------------------------------------
// GEMM+argmax+xo^2, 2 blocks/CU (the R16 fusion in the 2-block regime:
// co-resident blocks drift, so one block's xo stream overlaps the other's
// prologue/MFMA/restage). Verified best configuration (R18: 41.7us).
// ---------------------------------------------------------------------------
__global__ __launch_bounds__(NTHR, 2) void k_gemm(
    const float* __restrict__ xs, const float4* __restrict__ xo4,
    const unsigned char* __restrict__ gfrag,
    unsigned* __restrict__ maskp, double* __restrict__ partial) {
  const int tid = threadIdx.x, lane = tid & 63, wv = tid >> 6;
  const int g = lane >> 4, r16 = lane & 15;
  const int t0 = blockIdx.x * TM;
  const int tcol = t0 + 32 * wv + 2 * r16;   // float2 load column

  __shared__ __align__(16) unsigned char Bh[73728];  // one action-half of B
  __shared__ unsigned lmask[8];
  __shared__ double sdw[4];
  if (tid < 8) lmask[tid] = 0u;

  // stage action-half hv: 72 chunks of 1KB; wave wv does idx 18wv..18wv+17
#define STAGE_BH(hv)                                                          \
  {                                                                           \
    _Pragma("unroll") for (int idx = 0; idx < 18; ++idx) {                    \
      const int j = 18 * wv + idx;         /* 0..71: dst chunk */             \
      const int kkc = j >> 3, ic = j & 7;                                     \
      const unsigned char* src = gfrag +                                      \
          (size_t)(kkc * 16 + 8 * (hv) + ic) * 1024 + (size_t)lane * 16;      \
      unsigned char* dst = &Bh[j * 1024];                                     \
      __builtin_amdgcn_global_load_lds(                                       \
          (const __attribute__((address_space(1))) unsigned*)src,             \
          (__attribute__((address_space(3))) unsigned*)dst, 16, 0, 0);        \
    }                                                                         \
  }
  // A batch: 8 float2 loads (f-rows 32kkv+8g..+8g+7 at fixed 2 t's)
#define LOADB(slot, kkv)                                                      \
  {                                                                           \
    _Pragma("unroll") for (int j = 0; j < 8; ++j) {                           \
      int f = 32 * (kkv) + 8 * g + j;                                         \
      if ((kkv) == 8) f = f > 256 ? 256 : f; /* Gfrag zero rows cover pad */  \
      va[slot][j] = *(const float2*)(xs + (size_t)f * T_STEPS + tcol);        \
    }                                                                         \
  }

  float2 va[4][8];
  LOADB(0, 0) LOADB(1, 1) LOADB(2, 2) LOADB(3, 3)
  __builtin_amdgcn_sched_barrier(0);
  STAGE_BH(0)                      // after A batches 0-3, before 4-8
  __builtin_amdgcn_sched_barrier(0);

  // pack all A fragments while later batches stream in
  s16x8 af[9][2];   // [kk][tau], 72 VGPR
#pragma unroll
  for (int kk = 0; kk < 9; ++kk) {
    const int b = kk & 3;
    af[kk][0] = __builtin_bit_cast(s16x8, (u32x4){
        pack_bf(va[b][1].x, va[b][0].x), pack_bf(va[b][3].x, va[b][2].x),
        pack_bf(va[b][5].x, va[b][4].x), pack_bf(va[b][7].x, va[b][6].x)});
    af[kk][1] = __builtin_bit_cast(s16x8, (u32x4){
        pack_bf(va[b][1].y, va[b][0].y), pack_bf(va[b][3].y, va[b][2].y),
        pack_bf(va[b][5].y, va[b][4].y), pack_bf(va[b][7].y, va[b][6].y)});
    if (kk + 4 <= 8) LOADB(b, kk + 4)
  }
#undef LOADB

  __syncthreads();   // drains vmcnt (B half 0 staged) + all waves arrived

  // ---- two action-half passes; argmax folds across h in registers ----
  float bv[2][4]; int bc[2][4];
#pragma unroll
  for (int h = 0; h < 2; ++h) {
    if (h == 1) {
      __syncthreads();             // everyone done reading half 0
      STAGE_BH(1)
      __syncthreads();             // half 1 staged (vmcnt drained here)
    }
    f32x4 acc[2][8];   // [tau][n]
#pragma unroll
    for (int tau = 0; tau < 2; ++tau)
#pragma unroll
      for (int n = 0; n < 8; ++n) acc[tau][n] = (f32x4){0.f, 0.f, 0.f, 0.f};
#pragma unroll
    for (int kk = 0; kk < 9; ++kk) {
      const unsigned char* bp = &Bh[(kk * 8 * 64 + lane) * 16];
#pragma unroll
      for (int n = 0; n < 8; ++n) {
        const s16x8 bfr = *(const s16x8*)(bp + n * 1024);
        acc[0][n] = __builtin_amdgcn_mfma_f32_16x16x32_bf16(
            af[kk][0], bfr, acc[0][n], 0, 0, 0);
        acc[1][n] = __builtin_amdgcn_mfma_f32_16x16x32_bf16(
            af[kk][1], bfr, acc[1][n], 0, 0, 0);
      }
    }
    // fold into running argmax: a = 128h + 16n + r16 (ascending => first-min)
#pragma unroll
    for (int n = 0; n < 8; ++n) {
      const int c = 128 * h + 16 * n + r16;
#pragma unroll
      for (int tau = 0; tau < 2; ++tau)
#pragma unroll
        for (int q = 0; q < 4; ++q) {
          const float v = acc[tau][n][q];
          if (h == 0 && n == 0) { bv[tau][q] = v; bc[tau][q] = c; }
          else if (v > bv[tau][q]) { bv[tau][q] = v; bc[tau][q] = c; }
        }
    }
  }
#undef STAGE_BH

  // ---- issue xo round 0 + remainder early: argmax shuffles hide the ramp --
  const float4* xop = xo4 + (size_t)blockIdx.x * XO_PB + tid;
  float4 xv[2][8];
#pragma unroll
  for (int j = 0; j < 8; ++j) xv[0][j] = xop[j * 256];
  float4 wrem = (float4){0.f, 0.f, 0.f, 0.f};
  if (tid < 32) wrem = xo4[(size_t)blockIdx.x * XO_PB + 8192 + tid];

  // cross-lane (r16) argmax; each lane's t = t0+32wv+2*(4g+q)+tau
#pragma unroll
  for (int m = 1; m <= 8; m <<= 1) {
#pragma unroll
    for (int tau = 0; tau < 2; ++tau)
#pragma unroll
      for (int q = 0; q < 4; ++q) {
        const float ov = __shfl_xor(bv[tau][q], m);
        const int   oc = __shfl_xor(bc[tau][q], m);
        if (ov > bv[tau][q] || (ov == bv[tau][q] && oc < bc[tau][q])) {
          bv[tau][q] = ov; bc[tau][q] = oc;
        }
      }
  }
  if (r16 == 0) {
#pragma unroll
    for (int tau = 0; tau < 2; ++tau)
#pragma unroll
      for (int q = 0; q < 4; ++q)
        atomicOr(&lmask[bc[tau][q] >> 5], 1u << (bc[tau][q] & 31));
  }
  __syncthreads();
  if (tid < 8) maskp[blockIdx.x * 8 + tid] = lmask[tid];

  // ---- xo main: 4 rounds x 8 float4, double-buffered ----
  double ds = 0.0;
#pragma unroll
  for (int r = 0; r < 4; ++r) {
    if (r + 1 < 4) {
#pragma unroll
      for (int j = 0; j < 8; ++j)
        xv[(r + 1) & 1][j] = xop[(size_t)(r + 1) * 2048 + j * 256];
    }
    const float4* xc = xv[r & 1];
    float fs = 0.f;
#pragma unroll
    for (int j = 0; j < 8; ++j) {
      fs = fmaf(xc[j].x, xc[j].x, fs); fs = fmaf(xc[j].y, xc[j].y, fs);
      fs = fmaf(xc[j].z, xc[j].z, fs); fs = fmaf(xc[j].w, xc[j].w, fs);
    }
    ds += (double)fs;
  }
  {
    float fs = 0.f;
    fs = fmaf(wrem.x, wrem.x, fs); fs = fmaf(wrem.y, wrem.y, fs);
    fs = fmaf(wrem.z, wrem.z, fs); fs = fmaf(wrem.w, wrem.w, fs);
    ds += (double)fs;
  }
#pragma unroll
  for (int off = 32; off; off >>= 1) ds += __shfl_down(ds, off);
  if (lane == 0) sdw[wv] = ds;
  __syncthreads();
  if (tid == 0) partial[blockIdx.x] = sdw[0] + sdw[1] + sdw[2] + sdw[3];
}

// ---------------------------------------------------------------------------
// OR-reduce per-block masks (NBLK_G=512), then correction for columns t = a:
//   corrp[f] = sum_a sel[a] * ((G*xs)^2 - 2*(G*xs)*xo)
// ---------------------------------------------------------------------------
__global__ __launch_bounds__(256) void k_corr(
    const float* __restrict__ xs, const float* __restrict__ xo,
    const float* __restrict__ G, const unsigned* __restrict__ maskp,
    double* __restrict__ corrp) {
  __shared__ unsigned m8[8];
  const int tid = threadIdx.x;
  if (tid < 8) m8[tid] = 0u;
  __syncthreads();
  unsigned m = 0;
  for (int b = tid >> 3; b < NBLK_G; b += 32) m |= maskp[b * 8 + (tid & 7)];
  atomicOr(&m8[tid & 7], m);
  __syncthreads();
  const int f = blockIdx.x, a = tid;
  const bool sel = (m8[a >> 5] >> (a & 31)) & 1u;
  const float gv  = G[f * N_ACT + a];
  const float xsv = xs[(size_t)f * T_STEPS + a];
  const float xov = xo[(size_t)f * T_STEPS + a];
  const float gx  = gv * xsv;
  double acc = sel ? (double)(gx * (gx - 2.f * xov)) : 0.0;
#pragma unroll
  for (int off = 32; off; off >>= 1) acc += __shfl_down(acc, off);
  __shared__ double sdc[4];
  if ((tid & 63) == 0) sdc[tid >> 6] = acc;
  __syncthreads();
  if (tid == 0) corrp[f] = sdc[0] + sdc[1] + sdc[2] + sdc[3];
}

// ---------------------------------------------------------------------------
// Final reduction: partial[512] + corrp[257] -> loss
// ---------------------------------------------------------------------------
__global__ __launch_bounds__(256) void k_final(const double* __restrict__ partial,
                                               const double* __restrict__ corrp,
                                               float* __restrict__ out) {
  const int tid = threadIdx.x;
  double s = partial[tid] + partial[tid + 256] + corrp[tid];
  if (tid == 0) s += corrp[256];
#pragma unroll
  for (int off = 32; off; off >>= 1) s += __shfl_down(s, off);
  __shared__ double sd[4];
  if ((tid & 63) == 0) sd[tid >> 6] = s;
  __syncthreads();
  if (tid == 0)
    out[0] = (float)((sd[0] + sd[1] + sd[2] + sd[3]) /
                     ((double)F_BINS * (double)T_STEPS));
}

extern "C" void kernel_launch(void* const* d_in, const int* in_sizes, int n_in,
                              void* d_out, int out_size, void* d_ws, size_t ws_size,
                              hipStream_t stream) {
  const float* x_out    = (const float*)d_in[0];
  const float* x_source = (const float*)d_in[1];
  // d_in[2] (x_clean) is dead: argmin_a(clean_sum - proj) == argmax_a proj
  const float* G        = (const float*)d_in[3];

  char* ws = (char*)d_ws;
  double*        partial = (double*)(ws + WS_PART);
  double*        corrp   = (double*)(ws + WS_CORR);
  unsigned*      maskp   = (unsigned*)(ws + WS_MASK);
  unsigned char* gfrag   = (unsigned char*)(ws + WS_GFRAG);

  // no memset: partial, corrp, maskp, gfrag fully written every call
  k_prep <<<36, 256, 0, stream>>>(G, gfrag);
  k_gemm <<<NBLK_G, NTHR, 0, stream>>>(x_source, (const float4*)x_out,
                                       gfrag, maskp, partial);
  k_corr <<<F_BINS, 256, 0, stream>>>(x_source, x_out, G, maskp, corrp);
  k_final<<<1, 256, 0, stream>>>(partial, corrp, (float*)d_out);
}

// Round 22
// 40.761 us; speedup vs baseline: 2.4264x; 1.0385x over previous
//
#include <hip/hip_runtime.h>

#define F_BINS  257
#define T_STEPS 65536
#define N_ACT   256
#define TM      128           // t-columns per k_gemm block (4 waves x 32t)
#define NBLK_G  512           // T_STEPS / TM  -> 2 blocks/CU
#define NTHR    256           // 4 waves
#define XO_PB   8224          // float4 per block: 4210688/512 exact (32/thr + 32 rem)

typedef float f32x4 __attribute__((ext_vector_type(4)));
typedef short s16x8 __attribute__((ext_vector_type(8)));
typedef unsigned u32x4 __attribute__((ext_vector_type(4)));

// ws layout (all fully written every call - no memset needed):
//   [1024]   double partial[NBLK_G=512]  (per-block xo^2 sums)
//   [20480]  double corrp[257]           (per-f correction sums)
//   [24576]  unsigned maskp[NBLK_G*8]
//   [65536]  uchar Gfrag[147456]         (B frags: [kk][ng][lane][16B])
#define WS_PART  1024
#define WS_CORR  20480
#define WS_MASK  24576
#define WS_GFRAG 65536

__device__ __forceinline__ unsigned short f2bf_rne(float x) {
  unsigned u = __builtin_bit_cast(unsigned, x);
  return (unsigned short)((u + 0x7FFFu + ((u >> 16) & 1u)) >> 16);
}
// bf16(hi)<<16 | bf16(lo) by truncation: one v_perm_b32
__device__ __forceinline__ unsigned pack_bf(float hi, float lo) {
  return __builtin_amdgcn_perm(__builtin_bit_cast(unsigned, hi),
                               __builtin_bit_cast(unsigned, lo), 0x07060302u);
}

// ---------------------------------------------------------------------------
// B fragments in MFMA order:
// Gfrag[((kk*16+ng)*64+lane)*16] = 8 bf16 of G[f=32kk+8(lane>>4)+j][a=16ng+(lane&15)]
// ---------------------------------------------------------------------------
__global__ __launch_bounds__(256) void k_prep(const float* __restrict__ G,
                                              unsigned char* __restrict__ gfrag) {
  const int u = blockIdx.x * 256 + threadIdx.x;   // 0..9215
  const int lane = u & 63, ng = (u >> 6) & 15, kk = u >> 10;
  const int r16 = lane & 15, g = lane >> 4;
  const int a = ng * 16 + r16;
  unsigned short h[8];
#pragma unroll
  for (int j = 0; j < 8; ++j) {
    const int f = kk * 32 + 8 * g + j;
    h[j] = (f < F_BINS) ? f2bf_rne(G[f * N_ACT + a]) : (unsigned short)0;
  }
  u32x4 w;
#pragma unroll
  for (int i = 0; i < 4; ++i)
    w[i] = (unsigned)h[2 * i] | ((unsigned)h[2 * i + 1] << 16);
  *(u32x4*)(gfrag + (size_t)u * 16) = w;
}

// ---------------------------------------------------------------------------
// GEMM+argmax+xo^2, 2 blocks/CU (R18 core). Only delta vs R18/R21: xo
// rounds 0 AND 1 prefilled before the argmax shuffles (post-barrier region,
// so no vmcnt drain touches them), stream loop is consume-r / issue-r+2.
// ---------------------------------------------------------------------------
__global__ __launch_bounds__(NTHR, 2) void k_gemm(
    const float* __restrict__ xs, const float4* __restrict__ xo4,
    const unsigned char* __restrict__ gfrag,
    unsigned* __restrict__ maskp, double* __restrict__ partial) {
  const int tid = threadIdx.x, lane = tid & 63, wv = tid >> 6;
  const int g = lane >> 4, r16 = lane & 15;
  const int t0 = blockIdx.x * TM;
  const int tcol = t0 + 32 * wv + 2 * r16;   // float2 load column

  __shared__ __align__(16) unsigned char Bh[73728];  // one action-half of B
  __shared__ unsigned lmask[8];
  __shared__ double sdw[4];
  if (tid < 8) lmask[tid] = 0u;

  // stage action-half hv: 72 chunks of 1KB; wave wv does idx 18wv..18wv+17
#define STAGE_BH(hv)                                                          \
  {                                                                           \
    _Pragma("unroll") for (int idx = 0; idx < 18; ++idx) {                    \
      const int j = 18 * wv + idx;         /* 0..71: dst chunk */             \
      const int kkc = j >> 3, ic = j & 7;                                     \
      const unsigned char* src = gfrag +                                      \
          (size_t)(kkc * 16 + 8 * (hv) + ic) * 1024 + (size_t)lane * 16;      \
      unsigned char* dst = &Bh[j * 1024];                                     \
      __builtin_amdgcn_global_load_lds(                                       \
          (const __attribute__((address_space(1))) unsigned*)src,             \
          (__attribute__((address_space(3))) unsigned*)dst, 16, 0, 0);        \
    }                                                                         \
  }
  // A batch: 8 float2 loads (f-rows 32kkv+8g..+8g+7 at fixed 2 t's)
#define LOADB(slot, kkv)                                                      \
  {                                                                           \
    _Pragma("unroll") for (int j = 0; j < 8; ++j) {                           \
      int f = 32 * (kkv) + 8 * g + j;                                         \
      if ((kkv) == 8) f = f > 256 ? 256 : f; /* Gfrag zero rows cover pad */  \
      va[slot][j] = *(const float2*)(xs + (size_t)f * T_STEPS + tcol);        \
    }                                                                         \
  }

  float2 va[4][8];
  LOADB(0, 0) LOADB(1, 1) LOADB(2, 2) LOADB(3, 3)
  __builtin_amdgcn_sched_barrier(0);
  STAGE_BH(0)                      // after A batches 0-3, before 4-8
  __builtin_amdgcn_sched_barrier(0);

  // pack all A fragments while later batches stream in
  s16x8 af[9][2];   // [kk][tau], 72 VGPR
#pragma unroll
  for (int kk = 0; kk < 9; ++kk) {
    const int b = kk & 3;
    af[kk][0] = __builtin_bit_cast(s16x8, (u32x4){
        pack_bf(va[b][1].x, va[b][0].x), pack_bf(va[b][3].x, va[b][2].x),
        pack_bf(va[b][5].x, va[b][4].x), pack_bf(va[b][7].x, va[b][6].x)});
    af[kk][1] = __builtin_bit_cast(s16x8, (u32x4){
        pack_bf(va[b][1].y, va[b][0].y), pack_bf(va[b][3].y, va[b][2].y),
        pack_bf(va[b][5].y, va[b][4].y), pack_bf(va[b][7].y, va[b][6].y)});
    if (kk + 4 <= 8) LOADB(b, kk + 4)
  }
#undef LOADB

  __syncthreads();   // drains vmcnt (B half 0 staged) + all waves arrived

  // ---- two action-half passes; argmax folds across h in registers ----
  float bv[2][4]; int bc[2][4];
#pragma unroll
  for (int h = 0; h < 2; ++h) {
    if (h == 1) {
      __syncthreads();             // everyone done reading half 0
      STAGE_BH(1)
      __syncthreads();             // half 1 staged (vmcnt drained here)
    }
    f32x4 acc[2][8];   // [tau][n]
#pragma unroll
    for (int tau = 0; tau < 2; ++tau)
#pragma unroll
      for (int n = 0; n < 8; ++n) acc[tau][n] = (f32x4){0.f, 0.f, 0.f, 0.f};
#pragma unroll
    for (int kk = 0; kk < 9; ++kk) {
      const unsigned char* bp = &Bh[(kk * 8 * 64 + lane) * 16];
#pragma unroll
      for (int n = 0; n < 8; ++n) {
        const s16x8 bfr = *(const s16x8*)(bp + n * 1024);
        acc[0][n] = __builtin_amdgcn_mfma_f32_16x16x32_bf16(
            af[kk][0], bfr, acc[0][n], 0, 0, 0);
        acc[1][n] = __builtin_amdgcn_mfma_f32_16x16x32_bf16(
            af[kk][1], bfr, acc[1][n], 0, 0, 0);
      }
    }
    // fold into running argmax: a = 128h + 16n + r16 (ascending => first-min)
#pragma unroll
    for (int n = 0; n < 8; ++n) {
      const int c = 128 * h + 16 * n + r16;
#pragma unroll
      for (int tau = 0; tau < 2; ++tau)
#pragma unroll
        for (int q = 0; q < 4; ++q) {
          const float v = acc[tau][n][q];
          if (h == 0 && n == 0) { bv[tau][q] = v; bc[tau][q] = c; }
          else if (v > bv[tau][q]) { bv[tau][q] = v; bc[tau][q] = c; }
        }
    }
  }
#undef STAGE_BH

  // ---- issue xo rounds 0 AND 1 (+remainder) early: post-barrier region,
  //      argmax shuffles + lmask writeback hide the ramp (2 rounds deep) ----
  const float4* xop = xo4 + (size_t)blockIdx.x * XO_PB + tid;
  float4 xv[2][8];
#pragma unroll
  for (int j = 0; j < 8; ++j) xv[0][j] = xop[j * 256];
#pragma unroll
  for (int j = 0; j < 8; ++j) xv[1][j] = xop[2048 + j * 256];
  float4 wrem = (float4){0.f, 0.f, 0.f, 0.f};
  if (tid < 32) wrem = xo4[(size_t)blockIdx.x * XO_PB + 8192 + tid];

  // cross-lane (r16) argmax; each lane's t = t0+32wv+2*(4g+q)+tau
#pragma unroll
  for (int m = 1; m <= 8; m <<= 1) {
#pragma unroll
    for (int tau = 0; tau < 2; ++tau)
#pragma unroll
      for (int q = 0; q < 4; ++q) {
        const float ov = __shfl_xor(bv[tau][q], m);
        const int   oc = __shfl_xor(bc[tau][q], m);
        if (ov > bv[tau][q] || (ov == bv[tau][q] && oc < bc[tau][q])) {
          bv[tau][q] = ov; bc[tau][q] = oc;
        }
      }
  }
  if (r16 == 0) {
#pragma unroll
    for (int tau = 0; tau < 2; ++tau)
#pragma unroll
      for (int q = 0; q < 4; ++q)
        atomicOr(&lmask[bc[tau][q] >> 5], 1u << (bc[tau][q] & 31));
  }
  __syncthreads();
  if (tid < 8) maskp[blockIdx.x * 8 + tid] = lmask[tid];

  // ---- xo main: consume round r, then issue round r+2 into slot r&1 ----
  double ds = 0.0;
#pragma unroll
  for (int r = 0; r < 4; ++r) {
    float fs = 0.f;
#pragma unroll
    for (int j = 0; j < 8; ++j) {
      const float4 v = xv[r & 1][j];
      fs = fmaf(v.x, v.x, fs); fs = fmaf(v.y, v.y, fs);
      fs = fmaf(v.z, v.z, fs); fs = fmaf(v.w, v.w, fs);
    }
    ds += (double)fs;
    if (r + 2 < 4) {
#pragma unroll
      for (int j = 0; j < 8; ++j)
        xv[r & 1][j] = xop[(size_t)(r + 2) * 2048 + j * 256];
    }
  }
  {
    float fs = 0.f;
    fs = fmaf(wrem.x, wrem.x, fs); fs = fmaf(wrem.y, wrem.y, fs);
    fs = fmaf(wrem.z, wrem.z, fs); fs = fmaf(wrem.w, wrem.w, fs);
    ds += (double)fs;
  }
#pragma unroll
  for (int off = 32; off; off >>= 1) ds += __shfl_down(ds, off);
  if (lane == 0) sdw[wv] = ds;
  __syncthreads();
  if (tid == 0) partial[blockIdx.x] = sdw[0] + sdw[1] + sdw[2] + sdw[3];
}

// ---------------------------------------------------------------------------
// OR-reduce per-block masks (NBLK_G=512), then correction for columns t = a:
//   corrp[f] = sum_a sel[a] * ((G*xs)^2 - 2*(G*xs)*xo)
// ---------------------------------------------------------------------------
__global__ __launch_bounds__(256) void k_corr(
    const float* __restrict__ xs, const float* __restrict__ xo,
    const float* __restrict__ G, const unsigned* __restrict__ maskp,
    double* __restrict__ corrp) {
  __shared__ unsigned m8[8];
  const int tid = threadIdx.x;
  if (tid < 8) m8[tid] = 0u;
  __syncthreads();
  unsigned m = 0;
  for (int b = tid >> 3; b < NBLK_G; b += 32) m |= maskp[b * 8 + (tid & 7)];
  atomicOr(&m8[tid & 7], m);
  __syncthreads();
  const int f = blockIdx.x, a = tid;
  const bool sel = (m8[a >> 5] >> (a & 31)) & 1u;
  const float gv  = G[f * N_ACT + a];
  const float xsv = xs[(size_t)f * T_STEPS + a];
  const float xov = xo[(size_t)f * T_STEPS + a];
  const float gx  = gv * xsv;
  double acc = sel ? (double)(gx * (gx - 2.f * xov)) : 0.0;
#pragma unroll
  for (int off = 32; off; off >>= 1) acc += __shfl_down(acc, off);
  __shared__ double sdc[4];
  if ((tid & 63) == 0) sdc[tid >> 6] = acc;
  __syncthreads();
  if (tid == 0) corrp[f] = sdc[0] + sdc[1] + sdc[2] + sdc[3];
}

// ---------------------------------------------------------------------------
// Final reduction: partial[512] + corrp[257] -> loss
// ---------------------------------------------------------------------------
__global__ __launch_bounds__(256) void k_final(const double* __restrict__ partial,
                                               const double* __restrict__ corrp,
                                               float* __restrict__ out) {
  const int tid = threadIdx.x;
  double s = partial[tid] + partial[tid + 256] + corrp[tid];
  if (tid == 0) s += corrp[256];
#pragma unroll
  for (int off = 32; off; off >>= 1) s += __shfl_down(s, off);
  __shared__ double sd[4];
  if ((tid & 63) == 0) sd[tid >> 6] = s;
  __syncthreads();
  if (tid == 0)
    out[0] = (float)((sd[0] + sd[1] + sd[2] + sd[3]) /
                     ((double)F_BINS * (double)T_STEPS));
}

extern "C" void kernel_launch(void* const* d_in, const int* in_sizes, int n_in,
                              void* d_out, int out_size, void* d_ws, size_t ws_size,
                              hipStream_t stream) {
  const float* x_out    = (const float*)d_in[0];
  const float* x_source = (const float*)d_in[1];
  // d_in[2] (x_clean) is dead: argmin_a(clean_sum - proj) == argmax_a proj
  const float* G        = (const float*)d_in[3];

  char* ws = (char*)d_ws;
  double*        partial = (double*)(ws + WS_PART);
  double*        corrp   = (double*)(ws + WS_CORR);
  unsigned*      maskp   = (unsigned*)(ws + WS_MASK);
  unsigned char* gfrag   = (unsigned char*)(ws + WS_GFRAG);

  // no memset: partial, corrp, maskp, gfrag fully written every call
  k_prep <<<36, 256, 0, stream>>>(G, gfrag);
  k_gemm <<<NBLK_G, NTHR, 0, stream>>>(x_source, (const float4*)x_out,
                                       gfrag, maskp, partial);
  k_corr <<<F_BINS, 256, 0, stream>>>(x_source, x_out, G, maskp, corrp);
  k_final<<<1, 256, 0, stream>>>(partial, corrp, (float*)d_out);
}